// Round 7
// baseline (309.563 us; speedup 1.0000x reference)
//
#include <hip/hip_runtime.h>
#include <math.h>

#define TOKENS 16384
#define HID    4096
#define NEXP   64
#define TOPK   8
#define BT     32               // tokens per block
#define BK     64               // fp32 k per tile (256B per row)
#define NT     (HID / BK)       // 64 K-tiles
#define TAU    5e-4f            // ~4.6 sigma over 3-split logit error
#define REFINE_BLOCKS 256

typedef short          bf16x8 __attribute__((ext_vector_type(8)));
typedef unsigned short u16x8  __attribute__((ext_vector_type(8)));
typedef float          f32x4  __attribute__((ext_vector_type(4)));

__device__ __forceinline__ unsigned short bf16_rtn(float x) {
    unsigned u = __builtin_bit_cast(unsigned, x);
    u += 0x7FFFu + ((u >> 16) & 1u);
    return (unsigned short)(u >> 16);
}

__device__ __forceinline__ void splitf(float x, unsigned short& h, unsigned short& l) {
    h = bf16_rtn(x);
    float hf = __builtin_bit_cast(float, (unsigned)h << 16);
    l = bf16_rtn(x - hf);
}

// ---------- prep: W fp32 -> bf16 hi/lo (validated), zero flag counter -------
__global__ __launch_bounds__(256) void prep_kernel(
    const float* __restrict__ w,
    unsigned short* __restrict__ whi,
    unsigned short* __restrict__ wlo,
    int* __restrict__ flag_cnt)
{
    if (blockIdx.x == 0 && threadIdx.x == 0) flag_cnt[0] = 0;
    int gid = blockIdx.x * 256 + threadIdx.x;
    const f32x4* wp = (const f32x4*)w;
    f32x4 v0 = wp[gid * 2 + 0];
    f32x4 v1 = wp[gid * 2 + 1];
    u16x8 h8, l8;
    #pragma unroll
    for (int j = 0; j < 8; ++j) {
        float x = (j < 4) ? v0[j] : v1[j - 4];
        unsigned short h, l;
        splitf(x, h, l);
        h8[j] = h; l8[j] = l;
    }
    *(u16x8*)(whi + (size_t)gid * 8) = h8;
    *(u16x8*)(wlo + (size_t)gid * 8) = l8;
}

// ---------- pass 1: counted-vmcnt pipelined MFMA GEMM + top-8 ---------------
// 8 waves x (16 tok x 16 exp). A: 4-deep LDS buffers via global_load_lds,
// 3 tiles always in flight; raw s_barrier + asm vmcnt(5) -- NEVER drains in
// the main loop (T3/T4). B: preconverted bf16 hi/lo, reg double-buffered
// with static names (rule #20). Uniform 5 loads/iter via tail dummies.
__global__ __launch_bounds__(512, 4) void moe_gate_pass1(
    const float* __restrict__ hs,
    const unsigned short* __restrict__ whi,
    const unsigned short* __restrict__ wlo,
    float* __restrict__ out_idx_f,
    float* __restrict__ out_gate,
    int* __restrict__ flag_cnt,
    int* __restrict__ flag_list,
    int flag_cap)
{
    __shared__ __align__(16) char smem[32768];    // 4 x 8KB A buffers

    const int tid  = threadIdx.x;
    const int lane = tid & 63;
    const int wv   = tid >> 6;              // 0..7
    const int t0   = blockIdx.x * BT;
    const int h    = wv & 1;                // token half
    const int e4   = wv >> 1;               // expert quarter
    const int r16  = lane & 15;
    const int l4   = lane >> 4;

    // staging: wave wv stages rows [wv*4, wv*4+4); 1KB per gll issue.
    // Source pre-swizzled (float off ^ (row&7)<<2) == read-side XOR (rule #21).
    const int srow = wv * 4 + l4;
    const int soff = (r16 * 4) ^ ((srow & 7) << 2);
    const float* sgp = hs + (size_t)(t0 + srow) * HID + soff;

    // B frag pointers (validated: col=lane&15, k=(lane>>4)*8+j)
    const int col = e4 * 16 + r16;
    const unsigned short* bhp = whi + (size_t)col * HID + l4 * 8;
    const unsigned short* blp = wlo + (size_t)col * HID + l4 * 8;

    const int trow = h * 16 + r16;
    const int swz  = (r16 & 7) << 4;

    f32x4 acc = {0.f, 0.f, 0.f, 0.f};
    bf16x8 Bh0[2], Bl0[2], Bh1[2], Bl1[2];  // named double buffers (static idx)

#define STAGEm(BUF, T) { \
    const float* g = sgp + (size_t)(T) * BK; \
    __builtin_amdgcn_global_load_lds( \
        (const __attribute__((address_space(1))) void*)g, \
        (__attribute__((address_space(3))) void*)(smem + (BUF) * 8192 + wv * 1024), \
        16, 0, 0); }

#define LBm(S, T) { size_t kb = (size_t)(T) * BK; \
    Bh##S[0] = *(const bf16x8*)(bhp + kb); \
    Bh##S[1] = *(const bf16x8*)(bhp + kb + 32); \
    Bl##S[0] = *(const bf16x8*)(blp + kb); \
    Bl##S[1] = *(const bf16x8*)(blp + kb + 32); }

#define STEPm(T, CUR, NXT) { \
    int ts = (T) + 3 < NT ? (T) + 3 : 0; \
    int tb = (T) + 1 < NT ? (T) + 1 : 0; \
    STAGEm(((T) + 3) & 3, ts) \
    LBm(NXT, tb) \
    asm volatile("s_waitcnt vmcnt(5)" ::: "memory"); \
    __builtin_amdgcn_sched_barrier(0); \
    __builtin_amdgcn_s_barrier(); \
    __builtin_amdgcn_sched_barrier(0); \
    { const char* bp = smem + ((T) & 3) * 8192; \
      _Pragma("unroll") \
      for (int kk = 0; kk < 2; ++kk) { \
        int a0 = trow * 256 + kk * 128 + l4 * 32; \
        f32x4 f0 = *(const f32x4*)(bp + ((a0     ) ^ swz)); \
        f32x4 f1 = *(const f32x4*)(bp + ((a0 + 16) ^ swz)); \
        bf16x8 fah, fal; \
        _Pragma("unroll") \
        for (int j = 0; j < 8; ++j) { \
          float x = (j < 4) ? f0[j] : f1[j - 4]; \
          unsigned u = __builtin_bit_cast(unsigned, x); \
          unsigned r = u + 0x7FFFu + ((u >> 16) & 1u); \
          float hf = __builtin_bit_cast(float, r & 0xFFFF0000u); \
          float lof = x - hf; \
          unsigned ul = __builtin_bit_cast(unsigned, lof); \
          unsigned rl = ul + 0x7FFFu + ((ul >> 16) & 1u); \
          fah[j] = (short)(r >> 16); fal[j] = (short)(rl >> 16); } \
        acc = __builtin_amdgcn_mfma_f32_16x16x32_bf16(fah, Bh##CUR[kk], acc, 0, 0, 0); \
        acc = __builtin_amdgcn_mfma_f32_16x16x32_bf16(fah, Bl##CUR[kk], acc, 0, 0, 0); \
        acc = __builtin_amdgcn_mfma_f32_16x16x32_bf16(fal, Bh##CUR[kk], acc, 0, 0, 0); } } \
    __builtin_amdgcn_s_barrier(); \
    __builtin_amdgcn_sched_barrier(0); }

    // prologue: 3 A-tiles + B(0) in flight (7 outstanding)
    STAGEm(0, 0)
    STAGEm(1, 1)
    STAGEm(2, 2)
    LBm(0, 0)

    for (int tt = 0; tt < NT; tt += 2) {
        STEPm(tt,     0, 1)
        STEPm(tt + 1, 1, 0)
    }

#undef STAGEm
#undef LBm
#undef STEPm

    asm volatile("s_waitcnt vmcnt(0)" ::: "memory");   // drain tail dummies
    __syncthreads();

    // ---- epilogue: logits -> LDS [32][68], top-9 + gap + softmax ----
    float* lg = (float*)smem;
    #pragma unroll
    for (int r = 0; r < 4; ++r)
        lg[(h * 16 + l4 * 4 + r) * 68 + e4 * 16 + r16] = acc[r];
    __syncthreads();

    if (tid < BT) {
        const int t = tid;
        float v[9];
        int   id[9];
        #pragma unroll
        for (int j = 0; j < 9; ++j) { v[j] = -INFINITY; id[j] = -1; }
        for (int e = 0; e < NEXP; ++e) {
            float x = lg[t * 68 + e];
            if (x > v[8]) {
                int p = 8;
                while (p > 0 && v[p - 1] < x) {
                    v[p]  = v[p - 1];
                    id[p] = id[p - 1];
                    --p;
                }
                v[p]  = x;
                id[p] = e;
            }
        }
        float g = v[0] - v[1];
        #pragma unroll
        for (int j = 1; j < 8; ++j) g = fminf(g, v[j] - v[j + 1]);

        bool deferred = false;
        if (g < TAU) {
            int slot = atomicAdd(flag_cnt, 1);
            if (slot < flag_cap) {
                flag_list[slot] = t0 + t;
                deferred = true;
            }
        }
        if (!deferred) {
            float m = v[0];
            float ex[TOPK];
            float s = 0.0f;
            #pragma unroll
            for (int j = 0; j < TOPK; ++j) { ex[j] = expf(v[j] - m); s += ex[j]; }
            float inv = 1.0f / s;
            size_t base = (size_t)(t0 + t) * TOPK;
            #pragma unroll
            for (int j = 0; j < TOPK; ++j) {
                out_idx_f[base + j] = (float)id[j];
                out_gate[base + j]  = ex[j] * inv;
            }
        }
    }
}

// ---------- pass 2: fp64 exact recompute, coalesced (validated) -------------
__global__ __launch_bounds__(256) void moe_gate_refine(
    const float* __restrict__ hs,
    const float* __restrict__ w,
    float* __restrict__ out_idx_f,
    float* __restrict__ out_gate,
    const int* __restrict__ flag_cnt,
    const int* __restrict__ flag_list,
    int flag_cap)
{
    __shared__ float  hrow[HID];
    __shared__ double lgw[4][NEXP];
    __shared__ double lgd[NEXP];
    const int tid  = threadIdx.x;
    const int lane = tid & 63;
    const int wv   = tid >> 6;

    int n = flag_cnt[0];
    if (n > flag_cap) n = flag_cap;

    for (int fi = blockIdx.x; fi < n; fi += gridDim.x) {
        const int t = flag_list[fi];
        #pragma unroll
        for (int i = 0; i < 4; ++i)
            ((f32x4*)hrow)[tid + 256 * i] =
                ((const f32x4*)(hs + (size_t)t * HID))[tid + 256 * i];
        __syncthreads();

        for (int e = 0; e < NEXP; ++e) {
            const f32x4* wp = (const f32x4*)(w + (size_t)e * HID);
            double s0 = 0.0, s1 = 0.0, s2 = 0.0, s3 = 0.0;
            #pragma unroll
            for (int i = 0; i < 4; ++i) {
                f32x4 wf = wp[tid + 256 * i];
                f32x4 af = ((const f32x4*)hrow)[tid + 256 * i];
                s0 = fma((double)wf[0], (double)af[0], s0);
                s1 = fma((double)wf[1], (double)af[1], s1);
                s2 = fma((double)wf[2], (double)af[2], s2);
                s3 = fma((double)wf[3], (double)af[3], s3);
            }
            double d = (s0 + s1) + (s2 + s3);
            #pragma unroll
            for (int off = 32; off > 0; off >>= 1)
                d += __shfl_down(d, off, 64);
            if (lane == 0) lgw[wv][e] = d;
        }
        __syncthreads();
        if (tid < NEXP)
            lgd[tid] = (lgw[0][tid] + lgw[1][tid]) + (lgw[2][tid] + lgw[3][tid]);
        __syncthreads();

        if (tid == 0) {
            double v[TOPK];
            int    id[TOPK];
            #pragma unroll
            for (int j = 0; j < TOPK; ++j) { v[j] = -INFINITY; id[j] = -1; }
            for (int e = 0; e < NEXP; ++e) {
                double x = lgd[e];
                if (x > v[TOPK - 1]) {
                    int p = TOPK - 1;
                    while (p > 0 && v[p - 1] < x) {
                        v[p]  = v[p - 1];
                        id[p] = id[p - 1];
                        --p;
                    }
                    v[p]  = x;
                    id[p] = e;
                }
            }
            double m = v[0];
            double ex[TOPK];
            double s = 0.0;
            #pragma unroll
            for (int j = 0; j < TOPK; ++j) { ex[j] = exp(v[j] - m); s += ex[j]; }
            double inv = 1.0 / s;
            size_t base = (size_t)t * TOPK;
            #pragma unroll
            for (int j = 0; j < TOPK; ++j) {
                out_idx_f[base + j] = (float)id[j];
                out_gate[base + j]  = (float)(ex[j] * inv);
            }
        }
        __syncthreads();
    }
}

extern "C" void kernel_launch(void* const* d_in, const int* in_sizes, int n_in,
                              void* d_out, int out_size, void* d_ws, size_t ws_size,
                              hipStream_t stream) {
    const float* hs = (const float*)d_in[0];
    const float* w  = (const float*)d_in[1];
    float* out      = (float*)d_out;
    float* out_idx  = out;
    float* out_gate = out + (size_t)TOKENS * TOPK;

    unsigned short* whi = (unsigned short*)d_ws;
    unsigned short* wlo = whi + (size_t)NEXP * HID;
    int* flag_cnt  = (int*)(wlo + (size_t)NEXP * HID);
    int* flag_list = flag_cnt + 1;
    long flag_cap_l = ((long)ws_size - 2L * NEXP * HID * 2 - 16) / 4;
    int flag_cap = flag_cap_l < 0 ? 0 : (flag_cap_l > TOKENS ? TOKENS : (int)flag_cap_l);

    hipLaunchKernelGGL(prep_kernel, dim3(NEXP * HID / (256 * 8)), dim3(256), 0, stream,
                       w, whi, wlo, flag_cnt);
    hipLaunchKernelGGL(moe_gate_pass1, dim3(TOKENS / BT), dim3(512), 0, stream,
                       hs, whi, wlo, out_idx, out_gate, flag_cnt, flag_list, flag_cap);
    hipLaunchKernelGGL(moe_gate_refine, dim3(REFINE_BLOCKS), dim3(256), 0, stream,
                       hs, w, out_idx, out_gate, flag_cnt, flag_list, flag_cap);
}

// Round 8
// 282.209 us; speedup vs baseline: 1.0969x; 1.0969x over previous
//
#include <hip/hip_runtime.h>
#include <math.h>

#define TOKENS 16384
#define HID    4096
#define NEXP   64
#define TOPK   8
#define BT     64                // tokens per block
#define BK     256               // k per step (the big quantum)
#define NSTEPS (HID / BK)        // 16
#define TAU    5e-4f
#define REFINE_BLOCKS 256

typedef short          bf16x8 __attribute__((ext_vector_type(8)));
typedef unsigned short u16x8  __attribute__((ext_vector_type(8)));
typedef float          f32x4  __attribute__((ext_vector_type(4)));

// LDS layout (128 KB, single-buffered big tile, 64 rows x 256 k bf16 each):
#define AHI_OFF 0
#define ALO_OFF 32768
#define BHI_OFF 65536
#define BLO_OFF 98304

__device__ __forceinline__ unsigned short bf16_rtn(float x) {
    unsigned u = __builtin_bit_cast(unsigned, x);
    u += 0x7FFFu + ((u >> 16) & 1u);
    return (unsigned short)(u >> 16);
}

__device__ __forceinline__ void splitf(float x, unsigned short& h, unsigned short& l) {
    h = bf16_rtn(x);
    float hf = __builtin_bit_cast(float, (unsigned)h << 16);
    l = bf16_rtn(x - hf);
}

// ---------- prep: W fp32 -> bf16 hi/lo (validated), zero flag counter -------
__global__ __launch_bounds__(256) void prep_kernel(
    const float* __restrict__ w,
    unsigned short* __restrict__ whi,
    unsigned short* __restrict__ wlo,
    int* __restrict__ flag_cnt)
{
    if (blockIdx.x == 0 && threadIdx.x == 0) flag_cnt[0] = 0;
    int gid = blockIdx.x * 256 + threadIdx.x;
    const f32x4* wp = (const f32x4*)w;
    f32x4 v0 = wp[gid * 2 + 0];
    f32x4 v1 = wp[gid * 2 + 1];
    u16x8 h8, l8;
    #pragma unroll
    for (int j = 0; j < 8; ++j) {
        float x = (j < 4) ? v0[j] : v1[j - 4];
        unsigned short h, l;
        splitf(x, h, l);
        h8[j] = h; l8[j] = l;
    }
    *(u16x8*)(whi + (size_t)gid * 8) = h8;
    *(u16x8*)(wlo + (size_t)gid * 8) = l8;
}

// ---------- pass 1: big-quantum (BK=256) staged MFMA GEMM + top-8 -----------
// 1 block/CU (grid 256, 128KB LDS). Per step: 128 KB of A+B issued as
// register loads, double-banked so the NEXT step's 128 KB is in flight
// while the current step converts/computes -> in-flight volume >> latency-BW
// product. 2 barriers per 2.6us quantum (32 total vs r7's 128).
__global__ __launch_bounds__(512, 2) void moe_gate_pass1(
    const float* __restrict__ hs,
    const unsigned short* __restrict__ whi,
    const unsigned short* __restrict__ wlo,
    float* __restrict__ out_idx_f,
    float* __restrict__ out_gate,
    int* __restrict__ flag_cnt,
    int* __restrict__ flag_list,
    int flag_cap)
{
    __shared__ __align__(16) char smem[131072];

    const int tid  = threadIdx.x;
    const int lane = tid & 63;
    const int wv   = tid >> 6;               // 0..7
    const int t0   = blockIdx.x * BT;
    const int tokg = wv & 3;                 // 4 token groups of 16
    const int expg = wv >> 2;                // 2 expert halves of 32
    const int r16  = lane & 15;
    const int l4   = lane >> 4;

    // staging: thread -> (row 0..63, contiguous 32-float k-chunk)
    const int arow  = tid >> 3;              // token row AND expert row
    const int kseg  = (tid & 7) * 32;        // float/bf16 element offset
    const float*          agp = hs  + (size_t)(t0 + arow) * HID + kseg;
    const unsigned short* bhg = whi + (size_t)arow * HID + kseg;
    const unsigned short* blg = wlo + (size_t)arow * HID + kseg;
    const int wbase = arow * 512 + kseg * 2;        // bf16 byte base in tile
    const int wswz  = (arow & 7) << 4;

    // compute-side fragment addresses (validated 16x16x32 layouts)
    const int swz  = (r16 & 7) << 4;
    const int arf  = (tokg * 16 + r16) * 512 + l4 * 16;
    const int brf0 = (expg * 32 +      r16) * 512 + l4 * 16;
    const int brf1 = (expg * 32 + 16 + r16) * 512 + l4 * 16;

    f32x4 acc0 = {0.f, 0.f, 0.f, 0.f};
    f32x4 acc1 = {0.f, 0.f, 0.f, 0.f};

    f32x4 Ap[8], Aq[8];                      // A banks (static idx only)
    u16x8 Bhp[4], Blp[4], Bhq[4], Blq[4];    // B banks

#define LOADA(BANK, S) { \
    const f32x4* p = (const f32x4*)(agp + (size_t)(S) * BK); \
    _Pragma("unroll") for (int i = 0; i < 8; ++i) BANK[i] = p[i]; }

#define LOADB(BH, BL, S) { \
    const u16x8* ph = (const u16x8*)(bhg + (size_t)(S) * BK); \
    const u16x8* pl = (const u16x8*)(blg + (size_t)(S) * BK); \
    _Pragma("unroll") for (int c = 0; c < 4; ++c) { BH[c] = ph[c]; BL[c] = pl[c]; } }

#define CONVWRITE(AB, BH, BL) { \
    _Pragma("unroll") \
    for (int c = 0; c < 4; ++c) { \
        u16x8 h8, l8; \
        _Pragma("unroll") \
        for (int j = 0; j < 8; ++j) { \
            float x = (j < 4) ? AB[2 * c][j] : AB[2 * c + 1][j - 4]; \
            unsigned u  = __builtin_bit_cast(unsigned, x); \
            unsigned rr = u + 0x7FFFu + ((u >> 16) & 1u); \
            float hf = __builtin_bit_cast(float, rr & 0xFFFF0000u); \
            float lf = x - hf; \
            unsigned ul = __builtin_bit_cast(unsigned, lf); \
            unsigned rl = ul + 0x7FFFu + ((ul >> 16) & 1u); \
            h8[j] = (unsigned short)(rr >> 16); \
            l8[j] = (unsigned short)(rl >> 16); \
        } \
        int wo = (wbase + c * 16) ^ wswz; \
        *(u16x8*)(smem + AHI_OFF + wo) = h8; \
        *(u16x8*)(smem + ALO_OFF + wo) = l8; \
        *(u16x8*)(smem + BHI_OFF + wo) = BH[c]; \
        *(u16x8*)(smem + BLO_OFF + wo) = BL[c]; \
    } }

#define COMPUTE() { \
    _Pragma("unroll") \
    for (int kk = 0; kk < 8; ++kk) { \
        int ab = (arf  + kk * 64) ^ swz; \
        int b0 = (brf0 + kk * 64) ^ swz; \
        int b1 = (brf1 + kk * 64) ^ swz; \
        bf16x8 fah = *(const bf16x8*)(smem + AHI_OFF + ab); \
        bf16x8 fal = *(const bf16x8*)(smem + ALO_OFF + ab); \
        bf16x8 fbh0 = *(const bf16x8*)(smem + BHI_OFF + b0); \
        bf16x8 fbl0 = *(const bf16x8*)(smem + BLO_OFF + b0); \
        bf16x8 fbh1 = *(const bf16x8*)(smem + BHI_OFF + b1); \
        bf16x8 fbl1 = *(const bf16x8*)(smem + BLO_OFF + b1); \
        acc0 = __builtin_amdgcn_mfma_f32_16x16x32_bf16(fah, fbh0, acc0, 0, 0, 0); \
        acc1 = __builtin_amdgcn_mfma_f32_16x16x32_bf16(fah, fbh1, acc1, 0, 0, 0); \
        acc0 = __builtin_amdgcn_mfma_f32_16x16x32_bf16(fah, fbl0, acc0, 0, 0, 0); \
        acc1 = __builtin_amdgcn_mfma_f32_16x16x32_bf16(fah, fbl1, acc1, 0, 0, 0); \
        acc0 = __builtin_amdgcn_mfma_f32_16x16x32_bf16(fal, fbh0, acc0, 0, 0, 0); \
        acc1 = __builtin_amdgcn_mfma_f32_16x16x32_bf16(fal, fbh1, acc1, 0, 0, 0); \
    } }

    // prologue: step 0 into bank P
    LOADA(Ap, 0)
    LOADB(Bhp, Blp, 0)

    #pragma unroll 1
    for (int s = 0; s < NSTEPS; s += 2) {
        // even step: consume P, prefetch s+1 into Q
        if (s + 1 < NSTEPS) { LOADA(Aq, s + 1) LOADB(Bhq, Blq, s + 1) }
        CONVWRITE(Ap, Bhp, Blp)
        __syncthreads();
        COMPUTE()
        __syncthreads();
        // odd step: consume Q, prefetch s+2 into P
        if (s + 2 < NSTEPS) { LOADA(Ap, s + 2) LOADB(Bhp, Blp, s + 2) }
        CONVWRITE(Aq, Bhq, Blq)
        __syncthreads();
        COMPUTE()
        __syncthreads();
    }

#undef LOADA
#undef LOADB
#undef CONVWRITE
#undef COMPUTE

    // ---- epilogue: logits -> LDS [64][68], top-9 + gap + softmax ----
    float* lg = (float*)smem;
    #pragma unroll
    for (int r = 0; r < 4; ++r) {
        lg[(tokg * 16 + l4 * 4 + r) * 68 + expg * 32 +      r16] = acc0[r];
        lg[(tokg * 16 + l4 * 4 + r) * 68 + expg * 32 + 16 + r16] = acc1[r];
    }
    __syncthreads();

    if (tid < BT) {
        const int t = tid;
        float v[9];
        int   id[9];
        #pragma unroll
        for (int j = 0; j < 9; ++j) { v[j] = -INFINITY; id[j] = -1; }
        for (int e = 0; e < NEXP; ++e) {
            float x = lg[t * 68 + e];
            if (x > v[8]) {
                int p = 8;
                while (p > 0 && v[p - 1] < x) {
                    v[p]  = v[p - 1];
                    id[p] = id[p - 1];
                    --p;
                }
                v[p]  = x;
                id[p] = e;
            }
        }
        float g = v[0] - v[1];
        #pragma unroll
        for (int j = 1; j < 8; ++j) g = fminf(g, v[j] - v[j + 1]);

        bool deferred = false;
        if (g < TAU) {
            int slot = atomicAdd(flag_cnt, 1);
            if (slot < flag_cap) {
                flag_list[slot] = t0 + t;
                deferred = true;
            }
        }
        if (!deferred) {
            float m = v[0];
            float ex[TOPK];
            float s = 0.0f;
            #pragma unroll
            for (int j = 0; j < TOPK; ++j) { ex[j] = expf(v[j] - m); s += ex[j]; }
            float inv = 1.0f / s;
            size_t base = (size_t)(t0 + t) * TOPK;
            #pragma unroll
            for (int j = 0; j < TOPK; ++j) {
                out_idx_f[base + j] = (float)id[j];
                out_gate[base + j]  = ex[j] * inv;
            }
        }
    }
}

// ---------- pass 2: fp64 exact recompute, coalesced (validated) -------------
__global__ __launch_bounds__(256) void moe_gate_refine(
    const float* __restrict__ hs,
    const float* __restrict__ w,
    float* __restrict__ out_idx_f,
    float* __restrict__ out_gate,
    const int* __restrict__ flag_cnt,
    const int* __restrict__ flag_list,
    int flag_cap)
{
    __shared__ float  hrow[HID];
    __shared__ double lgw[4][NEXP];
    __shared__ double lgd[NEXP];
    const int tid  = threadIdx.x;
    const int lane = tid & 63;
    const int wv   = tid >> 6;

    int n = flag_cnt[0];
    if (n > flag_cap) n = flag_cap;

    for (int fi = blockIdx.x; fi < n; fi += gridDim.x) {
        const int t = flag_list[fi];
        #pragma unroll
        for (int i = 0; i < 4; ++i)
            ((f32x4*)hrow)[tid + 256 * i] =
                ((const f32x4*)(hs + (size_t)t * HID))[tid + 256 * i];
        __syncthreads();

        for (int e = 0; e < NEXP; ++e) {
            const f32x4* wp = (const f32x4*)(w + (size_t)e * HID);
            double s0 = 0.0, s1 = 0.0, s2 = 0.0, s3 = 0.0;
            #pragma unroll
            for (int i = 0; i < 4; ++i) {
                f32x4 wf = wp[tid + 256 * i];
                f32x4 af = ((const f32x4*)hrow)[tid + 256 * i];
                s0 = fma((double)wf[0], (double)af[0], s0);
                s1 = fma((double)wf[1], (double)af[1], s1);
                s2 = fma((double)wf[2], (double)af[2], s2);
                s3 = fma((double)wf[3], (double)af[3], s3);
            }
            double d = (s0 + s1) + (s2 + s3);
            #pragma unroll
            for (int off = 32; off > 0; off >>= 1)
                d += __shfl_down(d, off, 64);
            if (lane == 0) lgw[wv][e] = d;
        }
        __syncthreads();
        if (tid < NEXP)
            lgd[tid] = (lgw[0][tid] + lgw[1][tid]) + (lgw[2][tid] + lgw[3][tid]);
        __syncthreads();

        if (tid == 0) {
            double v[TOPK];
            int    id[TOPK];
            #pragma unroll
            for (int j = 0; j < TOPK; ++j) { v[j] = -INFINITY; id[j] = -1; }
            for (int e = 0; e < NEXP; ++e) {
                double x = lgd[e];
                if (x > v[TOPK - 1]) {
                    int p = TOPK - 1;
                    while (p > 0 && v[p - 1] < x) {
                        v[p]  = v[p - 1];
                        id[p] = id[p - 1];
                        --p;
                    }
                    v[p]  = x;
                    id[p] = e;
                }
            }
            double m = v[0];
            double ex[TOPK];
            double s = 0.0;
            #pragma unroll
            for (int j = 0; j < TOPK; ++j) { ex[j] = exp(v[j] - m); s += ex[j]; }
            double inv = 1.0 / s;
            size_t base = (size_t)t * TOPK;
            #pragma unroll
            for (int j = 0; j < TOPK; ++j) {
                out_idx_f[base + j] = (float)id[j];
                out_gate[base + j]  = (float)(ex[j] * inv);
            }
        }
        __syncthreads();
    }
}

extern "C" void kernel_launch(void* const* d_in, const int* in_sizes, int n_in,
                              void* d_out, int out_size, void* d_ws, size_t ws_size,
                              hipStream_t stream) {
    const float* hs = (const float*)d_in[0];
    const float* w  = (const float*)d_in[1];
    float* out      = (float*)d_out;
    float* out_idx  = out;
    float* out_gate = out + (size_t)TOKENS * TOPK;

    unsigned short* whi = (unsigned short*)d_ws;
    unsigned short* wlo = whi + (size_t)NEXP * HID;
    int* flag_cnt  = (int*)(wlo + (size_t)NEXP * HID);
    int* flag_list = flag_cnt + 1;
    long flag_cap_l = ((long)ws_size - 2L * NEXP * HID * 2 - 16) / 4;
    int flag_cap = flag_cap_l < 0 ? 0 : (flag_cap_l > TOKENS ? TOKENS : (int)flag_cap_l);

    hipLaunchKernelGGL(prep_kernel, dim3(NEXP * HID / (256 * 8)), dim3(256), 0, stream,
                       w, whi, wlo, flag_cnt);
    hipLaunchKernelGGL(moe_gate_pass1, dim3(TOKENS / BT), dim3(512), 0, stream,
                       hs, whi, wlo, out_idx, out_gate, flag_cnt, flag_list, flag_cap);
    hipLaunchKernelGGL(moe_gate_refine, dim3(REFINE_BLOCKS), dim3(256), 0, stream,
                       hs, w, out_idx, out_gate, flag_cnt, flag_list, flag_cap);
}

// Round 9
// 281.217 us; speedup vs baseline: 1.1008x; 1.0035x over previous
//
#include <hip/hip_runtime.h>
#include <math.h>

#define TOKENS 16384
#define HID    4096
#define NEXP   64
#define TOPK   8
#define BT     64                // tokens per block
#define BK     256               // k per step (big quantum)
#define NSTEPS (HID / BK)        // 16
#define TAU    5e-4f
#define REFINE_BLOCKS 256

typedef short          bf16x8 __attribute__((ext_vector_type(8)));
typedef unsigned short u16x8  __attribute__((ext_vector_type(8)));
typedef float          f32x4  __attribute__((ext_vector_type(4)));

// LDS: 64 rows x 256 k bf16 per tile, 4 tiles (A-hi, A-lo, B-hi, B-lo)
#define AHI_OFF 0
#define ALO_OFF 32768
#define BHI_OFF 65536
#define BLO_OFF 98304

__device__ __forceinline__ unsigned short bf16_rtn(float x) {
    unsigned u = __builtin_bit_cast(unsigned, x);
    u += 0x7FFFu + ((u >> 16) & 1u);
    return (unsigned short)(u >> 16);
}

__device__ __forceinline__ void splitf(float x, unsigned short& h, unsigned short& l) {
    h = bf16_rtn(x);
    float hf = __builtin_bit_cast(float, (unsigned)h << 16);
    l = bf16_rtn(x - hf);
}

// ---------- prep: W fp32 -> bf16 hi/lo (validated), zero flag counter -------
__global__ __launch_bounds__(256) void prep_kernel(
    const float* __restrict__ w,
    unsigned short* __restrict__ whi,
    unsigned short* __restrict__ wlo,
    int* __restrict__ flag_cnt)
{
    if (blockIdx.x == 0 && threadIdx.x == 0) flag_cnt[0] = 0;
    int gid = blockIdx.x * 256 + threadIdx.x;
    const f32x4* wp = (const f32x4*)w;
    f32x4 v0 = wp[gid * 2 + 0];
    f32x4 v1 = wp[gid * 2 + 1];
    u16x8 h8, l8;
    #pragma unroll
    for (int j = 0; j < 8; ++j) {
        float x = (j < 4) ? v0[j] : v1[j - 4];
        unsigned short h, l;
        splitf(x, h, l);
        h8[j] = h; l8[j] = l;
    }
    *(u16x8*)(whi + (size_t)gid * 8) = h8;
    *(u16x8*)(wlo + (size_t)gid * 8) = l8;
}

// ---------- pass 1: big-quantum MFMA GEMM, prefetch alive across barriers ---
// Fixes vs r8 (which serialized at 11us/step):
//  1. raw s_barrier (+lgkmcnt(0)+sched_barrier) -- NOT __syncthreads, whose
//     vmcnt(0) drain killed the double-banked prefetch every step.
//  2. swizzle key ((row ^ (pos>>6))&7)<<4 on BOTH ds_write and ds_read:
//     conflict-free b128 writes (8 lanes of a row -> 8 distinct slots) and
//     reads (slot = const ^ row per 8-lane group). Verified bijective.
__global__ __launch_bounds__(512, 2) void moe_gate_pass1(
    const float* __restrict__ hs,
    const unsigned short* __restrict__ whi,
    const unsigned short* __restrict__ wlo,
    float* __restrict__ out_idx_f,
    float* __restrict__ out_gate,
    int* __restrict__ flag_cnt,
    int* __restrict__ flag_list,
    int flag_cap)
{
    __shared__ __align__(16) char smem[131072];

    const int tid  = threadIdx.x;
    const int lane = tid & 63;
    const int wv   = tid >> 6;               // 0..7
    const int t0   = blockIdx.x * BT;
    const int tokg = wv & 3;                 // 4 token groups of 16
    const int expg = wv >> 2;                // 2 expert halves of 32
    const int r16  = lane & 15;
    const int l4   = lane >> 4;

    // staging: thread -> (row 0..63, contiguous 32-float k-chunk l0)
    const int arow = tid >> 3;
    const int l0   = tid & 7;
    const float*          agp = hs  + (size_t)(t0 + arow) * HID + l0 * 32;
    const unsigned short* bhg = whi + (size_t)arow * HID + l0 * 32;
    const unsigned short* blg = wlo + (size_t)arow * HID + l0 * 32;
    const int wrowb = arow * 512;
    const int wckey = ((arow ^ l0) & 7) << 4;       // write swizzle key
    const int wcb   = l0 * 64;                      // chunk byte base

    // compute-side row bases (validated 16x16x32 fragment layouts)
    const int trow = tokg * 16 + r16;
    const int arf  = trow * 512;
    const int brf0 = (expg * 32 +      r16) * 512;
    const int brf1 = (expg * 32 + 16 + r16) * 512;
    const int r7   = r16 & 7;
    const int pl4  = l4 * 16;

    f32x4 acc0 = {0.f, 0.f, 0.f, 0.f};
    f32x4 acc1 = {0.f, 0.f, 0.f, 0.f};

    f32x4 Ap[8], Aq[8];                      // A banks (static idx only)
    u16x8 Bhp[4], Blp[4], Bhq[4], Blq[4];    // B banks

#define LOADA(BANK, S) { \
    const f32x4* p = (const f32x4*)(agp + (size_t)(S) * BK); \
    _Pragma("unroll") for (int i = 0; i < 8; ++i) BANK[i] = p[i]; }

#define LOADB(BH, BL, S) { \
    const u16x8* ph = (const u16x8*)(bhg + (size_t)(S) * BK); \
    const u16x8* pl = (const u16x8*)(blg + (size_t)(S) * BK); \
    _Pragma("unroll") for (int c = 0; c < 4; ++c) { BH[c] = ph[c]; BL[c] = pl[c]; } }

#define CONVWRITE(AB, BH, BL) { \
    _Pragma("unroll") \
    for (int c = 0; c < 4; ++c) { \
        u16x8 h8, l8; \
        _Pragma("unroll") \
        for (int j = 0; j < 8; ++j) { \
            float x = (j < 4) ? AB[2 * c][j] : AB[2 * c + 1][j - 4]; \
            unsigned u  = __builtin_bit_cast(unsigned, x); \
            unsigned rr = u + 0x7FFFu + ((u >> 16) & 1u); \
            float hf = __builtin_bit_cast(float, rr & 0xFFFF0000u); \
            float lf = x - hf; \
            unsigned ul = __builtin_bit_cast(unsigned, lf); \
            unsigned rl = ul + 0x7FFFu + ((ul >> 16) & 1u); \
            h8[j] = (unsigned short)(rr >> 16); \
            l8[j] = (unsigned short)(rl >> 16); \
        } \
        int wo = wrowb + ((wcb + c * 16) ^ wckey); \
        *(u16x8*)(smem + AHI_OFF + wo) = h8; \
        *(u16x8*)(smem + ALO_OFF + wo) = l8; \
        *(u16x8*)(smem + BHI_OFF + wo) = BH[c]; \
        *(u16x8*)(smem + BLO_OFF + wo) = BL[c]; \
    } }

#define COMPUTE() { \
    _Pragma("unroll") \
    for (int kk = 0; kk < 8; ++kk) { \
        int pos = (kk * 64 + pl4) ^ (((r7 ^ kk) & 7) << 4); \
        int ab = arf  + pos; \
        int b0 = brf0 + pos; \
        int b1 = brf1 + pos; \
        bf16x8 fah  = *(const bf16x8*)(smem + AHI_OFF + ab); \
        bf16x8 fal  = *(const bf16x8*)(smem + ALO_OFF + ab); \
        bf16x8 fbh0 = *(const bf16x8*)(smem + BHI_OFF + b0); \
        bf16x8 fbl0 = *(const bf16x8*)(smem + BLO_OFF + b0); \
        bf16x8 fbh1 = *(const bf16x8*)(smem + BHI_OFF + b1); \
        bf16x8 fbl1 = *(const bf16x8*)(smem + BLO_OFF + b1); \
        acc0 = __builtin_amdgcn_mfma_f32_16x16x32_bf16(fah, fbh0, acc0, 0, 0, 0); \
        acc1 = __builtin_amdgcn_mfma_f32_16x16x32_bf16(fah, fbh1, acc1, 0, 0, 0); \
        acc0 = __builtin_amdgcn_mfma_f32_16x16x32_bf16(fah, fbl0, acc0, 0, 0, 0); \
        acc1 = __builtin_amdgcn_mfma_f32_16x16x32_bf16(fah, fbl1, acc1, 0, 0, 0); \
        acc0 = __builtin_amdgcn_mfma_f32_16x16x32_bf16(fal, fbh0, acc0, 0, 0, 0); \
        acc1 = __builtin_amdgcn_mfma_f32_16x16x32_bf16(fal, fbh1, acc1, 0, 0, 0); \
    } }

// write-visibility barrier: drain LDS writes only, NEVER vmcnt (prefetch lives)
#define BAR_W() { asm volatile("s_waitcnt lgkmcnt(0)" ::: "memory"); \
    __builtin_amdgcn_sched_barrier(0); \
    __builtin_amdgcn_s_barrier(); \
    __builtin_amdgcn_sched_barrier(0); }
// read-done barrier: MFMA issue already forced lgkm waits; just rendezvous
#define BAR_R() { __builtin_amdgcn_sched_barrier(0); \
    __builtin_amdgcn_s_barrier(); \
    __builtin_amdgcn_sched_barrier(0); }

    // prologue: step 0 into bank P
    LOADA(Ap, 0)
    LOADB(Bhp, Blp, 0)

    #pragma unroll 1
    for (int s = 0; s < NSTEPS; s += 2) {
        // even step: prefetch s+1 into Q, consume P
        if (s + 1 < NSTEPS) { LOADA(Aq, s + 1) LOADB(Bhq, Blq, s + 1) }
        CONVWRITE(Ap, Bhp, Blp)
        BAR_W()
        COMPUTE()
        BAR_R()
        // odd step: prefetch s+2 into P, consume Q
        if (s + 2 < NSTEPS) { LOADA(Ap, s + 2) LOADB(Bhp, Blp, s + 2) }
        CONVWRITE(Aq, Bhq, Blq)
        BAR_W()
        COMPUTE()
        BAR_R()
    }

#undef LOADA
#undef LOADB
#undef CONVWRITE
#undef COMPUTE
#undef BAR_W
#undef BAR_R

    __syncthreads();   // full drain before LDS reuse (loop left nothing in flight)

    // ---- epilogue: logits -> LDS [64][68], top-9 + gap + softmax ----
    float* lg = (float*)smem;
    #pragma unroll
    for (int r = 0; r < 4; ++r) {
        lg[(tokg * 16 + l4 * 4 + r) * 68 + expg * 32 +      r16] = acc0[r];
        lg[(tokg * 16 + l4 * 4 + r) * 68 + expg * 32 + 16 + r16] = acc1[r];
    }
    __syncthreads();

    if (tid < BT) {
        const int t = tid;
        float v[9];
        int   id[9];
        #pragma unroll
        for (int j = 0; j < 9; ++j) { v[j] = -INFINITY; id[j] = -1; }
        for (int e = 0; e < NEXP; ++e) {
            float x = lg[t * 68 + e];
            if (x > v[8]) {
                int p = 8;
                while (p > 0 && v[p - 1] < x) {
                    v[p]  = v[p - 1];
                    id[p] = id[p - 1];
                    --p;
                }
                v[p]  = x;
                id[p] = e;
            }
        }
        float g = v[0] - v[1];
        #pragma unroll
        for (int j = 1; j < 8; ++j) g = fminf(g, v[j] - v[j + 1]);

        bool deferred = false;
        if (g < TAU) {
            int slot = atomicAdd(flag_cnt, 1);
            if (slot < flag_cap) {
                flag_list[slot] = t0 + t;
                deferred = true;
            }
        }
        if (!deferred) {
            float m = v[0];
            float ex[TOPK];
            float s = 0.0f;
            #pragma unroll
            for (int j = 0; j < TOPK; ++j) { ex[j] = expf(v[j] - m); s += ex[j]; }
            float inv = 1.0f / s;
            size_t base = (size_t)(t0 + t) * TOPK;
            #pragma unroll
            for (int j = 0; j < TOPK; ++j) {
                out_idx_f[base + j] = (float)id[j];
                out_gate[base + j]  = ex[j] * inv;
            }
        }
    }
}

// ---------- pass 2: fp64 exact recompute, coalesced (validated) -------------
__global__ __launch_bounds__(256) void moe_gate_refine(
    const float* __restrict__ hs,
    const float* __restrict__ w,
    float* __restrict__ out_idx_f,
    float* __restrict__ out_gate,
    const int* __restrict__ flag_cnt,
    const int* __restrict__ flag_list,
    int flag_cap)
{
    __shared__ float  hrow[HID];
    __shared__ double lgw[4][NEXP];
    __shared__ double lgd[NEXP];
    const int tid  = threadIdx.x;
    const int lane = tid & 63;
    const int wv   = tid >> 6;

    int n = flag_cnt[0];
    if (n > flag_cap) n = flag_cap;

    for (int fi = blockIdx.x; fi < n; fi += gridDim.x) {
        const int t = flag_list[fi];
        #pragma unroll
        for (int i = 0; i < 4; ++i)
            ((f32x4*)hrow)[tid + 256 * i] =
                ((const f32x4*)(hs + (size_t)t * HID))[tid + 256 * i];
        __syncthreads();

        for (int e = 0; e < NEXP; ++e) {
            const f32x4* wp = (const f32x4*)(w + (size_t)e * HID);
            double s0 = 0.0, s1 = 0.0, s2 = 0.0, s3 = 0.0;
            #pragma unroll
            for (int i = 0; i < 4; ++i) {
                f32x4 wf = wp[tid + 256 * i];
                f32x4 af = ((const f32x4*)hrow)[tid + 256 * i];
                s0 = fma((double)wf[0], (double)af[0], s0);
                s1 = fma((double)wf[1], (double)af[1], s1);
                s2 = fma((double)wf[2], (double)af[2], s2);
                s3 = fma((double)wf[3], (double)af[3], s3);
            }
            double d = (s0 + s1) + (s2 + s3);
            #pragma unroll
            for (int off = 32; off > 0; off >>= 1)
                d += __shfl_down(d, off, 64);
            if (lane == 0) lgw[wv][e] = d;
        }
        __syncthreads();
        if (tid < NEXP)
            lgd[tid] = (lgw[0][tid] + lgw[1][tid]) + (lgw[2][tid] + lgw[3][tid]);
        __syncthreads();

        if (tid == 0) {
            double v[TOPK];
            int    id[TOPK];
            #pragma unroll
            for (int j = 0; j < TOPK; ++j) { v[j] = -INFINITY; id[j] = -1; }
            for (int e = 0; e < NEXP; ++e) {
                double x = lgd[e];
                if (x > v[TOPK - 1]) {
                    int p = TOPK - 1;
                    while (p > 0 && v[p - 1] < x) {
                        v[p]  = v[p - 1];
                        id[p] = id[p - 1];
                        --p;
                    }
                    v[p]  = x;
                    id[p] = e;
                }
            }
            double m = v[0];
            double ex[TOPK];
            double s = 0.0;
            #pragma unroll
            for (int j = 0; j < TOPK; ++j) { ex[j] = exp(v[j] - m); s += ex[j]; }
            double inv = 1.0 / s;
            size_t base = (size_t)t * TOPK;
            #pragma unroll
            for (int j = 0; j < TOPK; ++j) {
                out_idx_f[base + j] = (float)id[j];
                out_gate[base + j]  = (float)(ex[j] * inv);
            }
        }
        __syncthreads();
    }
}

extern "C" void kernel_launch(void* const* d_in, const int* in_sizes, int n_in,
                              void* d_out, int out_size, void* d_ws, size_t ws_size,
                              hipStream_t stream) {
    const float* hs = (const float*)d_in[0];
    const float* w  = (const float*)d_in[1];
    float* out      = (float*)d_out;
    float* out_idx  = out;
    float* out_gate = out + (size_t)TOKENS * TOPK;

    unsigned short* whi = (unsigned short*)d_ws;
    unsigned short* wlo = whi + (size_t)NEXP * HID;
    int* flag_cnt  = (int*)(wlo + (size_t)NEXP * HID);
    int* flag_list = flag_cnt + 1;
    long flag_cap_l = ((long)ws_size - 2L * NEXP * HID * 2 - 16) / 4;
    int flag_cap = flag_cap_l < 0 ? 0 : (flag_cap_l > TOKENS ? TOKENS : (int)flag_cap_l);

    hipLaunchKernelGGL(prep_kernel, dim3(NEXP * HID / (256 * 8)), dim3(256), 0, stream,
                       w, whi, wlo, flag_cnt);
    hipLaunchKernelGGL(moe_gate_pass1, dim3(TOKENS / BT), dim3(512), 0, stream,
                       hs, whi, wlo, out_idx, out_gate, flag_cnt, flag_list, flag_cap);
    hipLaunchKernelGGL(moe_gate_refine, dim3(REFINE_BLOCKS), dim3(256), 0, stream,
                       hs, w, out_idx, out_gate, flag_cnt, flag_list, flag_cap);
}